// Round 1
// 233.083 us; speedup vs baseline: 1.0050x; 1.0050x over previous
//
#include <hip/hip_runtime.h>
#include <hip/hip_bf16.h>

typedef __bf16 bf16_t;
typedef __bf16 bf16x8 __attribute__((ext_vector_type(8)));
typedef float f32x4 __attribute__((ext_vector_type(4)));
typedef unsigned short u16x4 __attribute__((ext_vector_type(4)));

// Operand order: A = weight fragment (gate rows), B = x/h fragment (batch).
// C/D: col(lane&15) = batch, row(quad*4+r) = gate row.
#define MFMA16(a, b, c) __builtin_amdgcn_mfma_f32_16x16x32_bf16((a), (b), (c), 0, 0, 0)

#define BATCH 4096
#define SEQN 128
#define HN 256
#define NLABELS 100
#define TSTEPS 32
#define LEN_VN 1500
#define IPD_VN 256

// Workspace layout (bytes) — unchanged
#define OFF_LENT   0u           // 1500*64*4 = 384000
#define OFF_IPDT   384000u      // 256*64*4  = 65536
#define OFF_WIH    449536u      // 768*256*2 = 393216
#define OFF_WHH    842752u      // 393216
#define OFF_GI     1235968u     // 4096*32*768*2 = 201326592

__device__ __forceinline__ float sigf(float x) {
    return __builtin_amdgcn_rcpf(1.f + __expf(-x));
}
__device__ __forceinline__ float tanh_fast(float x) {
    return 2.f * __builtin_amdgcn_rcpf(1.f + __expf(-2.f * x)) - 1.f;
}
__device__ __forceinline__ float b2f(unsigned short v) {
    union { unsigned u; float f; } c; c.u = ((unsigned)v) << 16; return c.f;
}
__device__ __forceinline__ f32x4 b2f4(u16x4 v) {
    f32x4 o;
    #pragma unroll
    for (int r = 0; r < 4; ++r) o[r] = b2f(v[r]);
    return o;
}
__device__ __forceinline__ unsigned short f2b(float f) {
    union { bf16_t h; unsigned short s; } c; c.h = (bf16_t)f; return c.s;
}

// LDS-only barrier: does not drain vmcnt; global loads/stores stay in flight.
__device__ __forceinline__ void barrier_lds() {
    asm volatile("s_waitcnt lgkmcnt(0)\n\ts_barrier" ::: "memory");
}
// Per-wave drain of all outstanding global ops (phase boundary).
__device__ __forceinline__ void wait_vm0() {
    asm volatile("s_waitcnt vmcnt(0)" ::: "memory");
}

// ---------------------------------------------------------------------------
// K1: prep — UNCHANGED (coalesced table build + weight fragments).
// frag order: wfrag[ct(48)][kt(8)][lane(64)][8], value =
//   W[ct*16 + (lane&15)][kt*32 + (lane>>4)*8 + j]
// ---------------------------------------------------------------------------
#define PREP_TBL_BLOCKS 110
__global__ void prep_kernel(const float* __restrict__ len_emb,
                            const float* __restrict__ ipd_emb,
                            const float* __restrict__ fc_w,
                            const float* __restrict__ fc_b,
                            const float* __restrict__ w_ih,
                            const float* __restrict__ w_hh,
                            float* __restrict__ lenT, float* __restrict__ ipdT,
                            bf16_t* __restrict__ wfrag_ih,
                            bf16_t* __restrict__ wfrag_hh) {
    const int bid = blockIdx.x, tid = threadIdx.x;
    if (bid < PREP_TBL_BLOCKS) {
        __shared__ float w_lds[64 * 132];    // fc_w [e][j], stride 132 (16B-aligned rows)
        __shared__ float emb_lds[16 * 64];   // 16 table rows
        const int row0 = bid * 16;

        #pragma unroll
        for (int k = 0; k < 8; ++k) {
            const int l = k * 1024 + tid * 4;
            const int e = l >> 7, j = l & 127;
            *(f32x4*)(w_lds + e * 132 + j) = *(const f32x4*)(fc_w + l);
        }
        {
            const int r = tid >> 4;
            const int c = (tid & 15) * 4;
            const int grow = row0 + r;
            f32x4 v = {};
            if (grow < LEN_VN)               v = *(const f32x4*)(len_emb + grow * 64 + c);
            else if (grow < LEN_VN + IPD_VN) v = *(const f32x4*)(ipd_emb + (grow - LEN_VN) * 64 + c);
            *(f32x4*)(emb_lds + r * 64 + c) = v;
        }
        __syncthreads();

        const int e = tid & 63;
        const int r0 = tid >> 6;
        const float* wrow_lo = w_lds + e * 132;
        #pragma unroll
        for (int rr = 0; rr < 4; ++rr) {
            const int r = r0 + rr * 4;
            const int grow = row0 + r;
            if (grow >= LEN_VN + IPD_VN) break;
            const bool is_len = grow < LEN_VN;
            const float* wrow = is_len ? wrow_lo : (wrow_lo + 64);
            f32x4 acc = {};
            #pragma unroll
            for (int c = 0; c < 16; ++c) {
                f32x4 wv = *(const f32x4*)(wrow + c * 4);
                f32x4 ev = *(const f32x4*)(emb_lds + r * 64 + c * 4);
                acc += wv * ev;
            }
            float s = acc[0] + acc[1] + acc[2] + acc[3] + (is_len ? fc_b[e] : 0.f);
            if (is_len) lenT[grow * 64 + e] = s;
            else        ipdT[(grow - LEN_VN) * 64 + e] = s;
        }
    } else {
        const int flat = (bid - PREP_TBL_BLOCKS) * 256 + tid;
        const int which = flat / 24576;
        const int rem = flat % 24576;
        const int c = rem >> 9;
        const int kt = (rem >> 6) & 7;
        const int lane = rem & 63;
        const int g = c * 16 + (lane & 15);
        const int k0 = kt * 32 + (lane >> 4) * 8;
        const float* src = (which == 0 ? w_ih : w_hh) + g * 256 + k0;
        bf16_t* dst = (which == 0 ? wfrag_ih : wfrag_hh) + ((c * 8 + kt) * 64 + lane) * 8;
        f32x4 s0 = *(const f32x4*)(src);
        f32x4 s1 = *(const f32x4*)(src + 4);
        bf16x8 o;
        #pragma unroll
        for (int j = 0; j < 4; ++j) { o[j] = (bf16_t)s0[j]; o[4 + j] = (bf16_t)s1[j]; }
        *(bf16x8*)dst = o;
    }
}

// ---------------------------------------------------------------------------
// K2: FUSED input-GEMM + GRU, RESTRUCTURED for LDS bandwidth:
//   8 waves (512 thr), 6 gate-tiles per wave: ct(g,s) = g*16 + 2*w + s.
//   5 tiles in VGPRs (160 VGPR), only 1 tile (n-gate, s=1) in LDS.
//   Biases staged in LDS (broadcast reads) to hold VGPR pressure ~230.
//   LDS reads/CU/t: 256 KB -> ~136 KB; weight LDS re-reads mostly gone.
// ---------------------------------------------------------------------------
__global__ void __launch_bounds__(512, 2)
fused_kernel(const int* __restrict__ len_x, const int* __restrict__ ipd_x,
             const float* __restrict__ lenT, const float* __restrict__ ipdT,
             const bf16_t* __restrict__ wfrag_ih,
             const bf16_t* __restrict__ wfrag_hh,
             const float* __restrict__ b_ih, const float* __restrict__ b_hh,
             bf16_t* gi,
             const float* __restrict__ out_w,
             const float* __restrict__ out_b,
             float* __restrict__ out) {
    __shared__ char smem[86016];
    bf16_t* wlds = (bf16_t*)smem;                 // 64 KB: per-wave 6th tile (8 w x 8 KB)
    bf16_t* dbuf = (bf16_t*)(smem + 65536);       // 16 KB: x-stage / h double buf
    float* bias_lds = (float*)(smem + 81920);     // [768] b_ih(+b_hh rz) ; [768..1024) b_hh n
    float* h_fin = (float*)smem;                  // aliases wlds (post-loop)

    const int tid = threadIdx.x;
    const int lane = tid & 63;
    const int w = tid >> 6;          // wave 0..7
    const int bt = blockIdx.x;
    const int quad = lane >> 4;
    const int b = lane & 15;
    const int c2w = 2 * w;

    bf16_t* gib = gi + (size_t)bt * 48 * 32 * 256 + lane * 4;
    const bf16_t* wb = &wlds[w * 4096 + lane * 8];

    // stage biases: [0,512): b_ih+b_hh (r,z); [512,768): b_ih (n); [768,1024): b_hh (n)
    for (int i = tid; i < 768; i += 512)
        bias_lds[i] = b_ih[i] + (i < 512 ? b_hh[i] : 0.f);
    for (int i = tid; i < 256; i += 512)
        bias_lds[768 + i] = b_hh[512 + i];

    // ===================== PHASE 1: input-side GEMM ========================
    {
        bf16x8 wri[5][8];
        #pragma unroll
        for (int i = 0; i < 5; ++i) {
            const int ct = (i >> 1) * 16 + c2w + (i & 1);
            #pragma unroll
            for (int kt = 0; kt < 8; ++kt)
                wri[i][kt] = *(const bf16x8*)(wfrag_ih + ((ct * 8 + kt) * 64 + lane) * 8);
        }
        {
            const int ct = 33 + c2w;   // (n, s=1) -> LDS
            #pragma unroll
            for (int kt = 0; kt < 8; ++kt)
                *(bf16x8*)&wlds[w * 4096 + kt * 512 + lane * 8] =
                    *(const bf16x8*)(wfrag_ih + ((ct * 8 + kt) * 64 + lane) * 8);
        }

        // gather: 512 threads, identical mapping to baseline
        const int pr = tid >> 3;
        const int sub8 = tid & 7;
        const int grow = pr & 15;
        const int p = pr >> 4;
        const int e0 = sub8 * 8;
        const int b_row = bt * 16 + grow;
        const int goff = (2 * p + (sub8 >> 2)) * 512 + ((sub8 & 3) * 16 + grow) * 8;

        auto do_gather = [&](int t) {
            const int seq = t * 4 + p;
            const int v1 = len_x[b_row * SEQN + seq];
            const int v2 = ipd_x[b_row * SEQN + seq];
            const float* lp = lenT + v1 * 64 + e0;
            const float* ip = ipdT + v2 * 64 + e0;
            f32x4 a0 = *(const f32x4*)lp + *(const f32x4*)ip;
            f32x4 a1 = *(const f32x4*)(lp + 4) + *(const f32x4*)(ip + 4);
            bf16x8 o;
            #pragma unroll
            for (int j = 0; j < 4; ++j) { o[j] = (bf16_t)a0[j]; o[4 + j] = (bf16_t)a1[j]; }
            *(bf16x8*)&dbuf[(t & 1) * 4096 + goff] = o;
        };

        do_gather(0);

        for (int t = 0; t < TSTEPS; ++t) {
            barrier_lds();
            if (t + 1 < TSTEPS) do_gather(t + 1);

            f32x4 acc[6];
            #pragma unroll
            for (int i = 0; i < 6; ++i)
                acc[i] = *(const f32x4*)(bias_lds + (i >> 1) * 256 + (c2w + (i & 1)) * 16 + quad * 4);

            const bf16_t* ab = &dbuf[(t & 1) * 4096 + lane * 8];
            #pragma unroll
            for (int kt = 0; kt < 8; ++kt) {
                bf16x8 xf = *(const bf16x8*)(ab + kt * 512);
                bf16x8 w5 = *(const bf16x8*)(wb + kt * 512);
                acc[0] = MFMA16(wri[0][kt], xf, acc[0]);
                acc[1] = MFMA16(wri[1][kt], xf, acc[1]);
                acc[2] = MFMA16(wri[2][kt], xf, acc[2]);
                acc[3] = MFMA16(wri[3][kt], xf, acc[3]);
                acc[4] = MFMA16(wri[4][kt], xf, acc[4]);
                acc[5] = MFMA16(w5, xf, acc[5]);
            }

            #pragma unroll
            for (int i = 0; i < 6; ++i) {
                const int ct = (i >> 1) * 16 + c2w + (i & 1);
                u16x4 o;
                #pragma unroll
                for (int r = 0; r < 4; ++r) o[r] = f2b(acc[i][r]);
                *(u16x4*)(gib + ((size_t)ct * 32 + t) * 256) = o;
            }
        }
    }

    // ===================== PHASE boundary ==================================
    barrier_lds();
    wait_vm0();   // gi stores (same lane) must land before ph2 reloads them

    // ===================== PHASE 2: recurrent GRU ==========================
    bf16_t* h_lds = dbuf;

    bf16x8 wr[5][8];
    #pragma unroll
    for (int i = 0; i < 5; ++i) {
        const int ct = (i >> 1) * 16 + c2w + (i & 1);
        #pragma unroll
        for (int kt = 0; kt < 8; ++kt)
            wr[i][kt] = *(const bf16x8*)(wfrag_hh + ((ct * 8 + kt) * 64 + lane) * 8);
    }
    {
        const int ct = 33 + c2w;
        #pragma unroll
        for (int kt = 0; kt < 8; ++kt)
            *(bf16x8*)&wlds[w * 4096 + kt * 512 + lane * 8] =
                *(const bf16x8*)(wfrag_hh + ((ct * 8 + kt) * 64 + lane) * 8);
    }

    for (int i = tid; i < 4096; i += 512) h_lds[4096 + i] = (bf16_t)0.f;

    const int j00 = (c2w + 0) * 16 + 4 * quad;
    const int j01 = (c2w + 1) * 16 + 4 * quad;
    const int woff0 = (j00 >> 5) * 512 + (((j00 >> 3) & 3) * 16 + b) * 8 + (j00 & 7);
    const int woff1 = (j01 >> 5) * 512 + (((j01 >> 3) & 3) * 16 + b) * 8 + (j01 & 7);

    u16x4 gc[6];
    #pragma unroll
    for (int i = 0; i < 6; ++i) {
        const int ct = (i >> 1) * 16 + c2w + (i & 1);
        gc[i] = *(const u16x4*)(gib + ((size_t)ct * 32) * 256);
    }

    f32x4 hprev0 = {}, hprev1 = {};

    for (int t = 0; t < TSTEPS; ++t) {
        barrier_lds();

        f32x4 acc[6];
        acc[0] = b2f4(gc[0]); acc[1] = b2f4(gc[1]);
        acc[2] = b2f4(gc[2]); acc[3] = b2f4(gc[3]);
        acc[4] = *(const f32x4*)(bias_lds + 768 + (c2w + 0) * 16 + quad * 4);
        acc[5] = *(const f32x4*)(bias_lds + 768 + (c2w + 1) * 16 + quad * 4);
        u16x4 g4 = gc[4], g5 = gc[5];

        if (t + 1 < TSTEPS) {
            #pragma unroll
            for (int i = 0; i < 6; ++i) {
                const int ct = (i >> 1) * 16 + c2w + (i & 1);
                gc[i] = *(const u16x4*)(gib + ((size_t)ct * 32 + t + 1) * 256);
            }
        }

        const bf16_t* hb = &h_lds[((t + 1) & 1) * 4096 + lane * 8];
        #pragma unroll
        for (int kt = 0; kt < 8; ++kt) {
            bf16x8 hf = *(const bf16x8*)(hb + kt * 512);
            bf16x8 w5 = *(const bf16x8*)(wb + kt * 512);
            acc[0] = MFMA16(wr[0][kt], hf, acc[0]);
            acc[1] = MFMA16(wr[1][kt], hf, acc[1]);
            acc[2] = MFMA16(wr[2][kt], hf, acc[2]);
            acc[3] = MFMA16(wr[3][kt], hf, acc[3]);
            acc[4] = MFMA16(wr[4][kt], hf, acc[4]);
            acc[5] = MFMA16(w5, hf, acc[5]);
        }

        // s=0: r=acc0, z=acc2, h_n=acc4, i_n=g4 ; s=1: r=acc1, z=acc3, h_n=acc5, i_n=g5
        f32x4 rg0, zg0, rg1, zg1;
        #pragma unroll
        for (int r = 0; r < 4; ++r) {
            rg0[r] = sigf(acc[0][r]); rg1[r] = sigf(acc[1][r]);
            zg0[r] = sigf(acc[2][r]); zg1[r] = sigf(acc[3][r]);
        }
        f32x4 u0 = b2f4(g4) + rg0 * acc[4];
        f32x4 u1 = b2f4(g5) + rg1 * acc[5];
        f32x4 ng0, ng1;
        #pragma unroll
        for (int r = 0; r < 4; ++r) { ng0[r] = tanh_fast(u0[r]); ng1[r] = tanh_fast(u1[r]); }
        f32x4 h0 = ng0 + zg0 * (hprev0 - ng0);
        f32x4 h1 = ng1 + zg1 * (hprev1 - ng1);
        hprev0 = h0; hprev1 = h1;

        u16x4 o0, o1;
        #pragma unroll
        for (int r = 0; r < 4; ++r) { o0[r] = f2b(h0[r]); o1[r] = f2b(h1[r]); }
        *(u16x4*)(&h_lds[(t & 1) * 4096 + woff0]) = o0;
        *(u16x4*)(&h_lds[(t & 1) * 4096 + woff1]) = o1;
    }

    __syncthreads();

    *(f32x4*)(h_fin + b * 260 + j00) = hprev0;
    *(f32x4*)(h_fin + b * 260 + j01) = hprev1;
    __syncthreads();

    for (int i = tid; i < 16 * NLABELS; i += 512) {
        const int row = i / NLABELS;
        const int cl = i - row * NLABELS;
        const f32x4* wrow = (const f32x4*)(out_w + cl * 256);
        const f32x4* hr = (const f32x4*)(h_fin + row * 260);
        f32x4 acc = {0.f, 0.f, 0.f, 0.f};
        #pragma unroll 4
        for (int k = 0; k < 64; ++k) acc += hr[k] * wrow[k];
        out[(bt * 16 + row) * NLABELS + cl] =
            out_b[cl] + acc[0] + acc[1] + acc[2] + acc[3];
    }
}

// ---------------------------------------------------------------------------
extern "C" void kernel_launch(void* const* d_in, const int* in_sizes, int n_in,
                              void* d_out, int out_size, void* d_ws, size_t ws_size,
                              hipStream_t stream) {
    (void)in_sizes; (void)n_in; (void)out_size; (void)ws_size;
    const int*   len_x   = (const int*)d_in[0];
    const int*   ipd_x   = (const int*)d_in[1];
    const float* len_emb = (const float*)d_in[2];
    const float* ipd_emb = (const float*)d_in[3];
    const float* fc_w    = (const float*)d_in[4];
    const float* fc_b    = (const float*)d_in[5];
    const float* w_ih    = (const float*)d_in[6];
    const float* w_hh    = (const float*)d_in[7];
    const float* b_ih    = (const float*)d_in[8];
    const float* b_hh    = (const float*)d_in[9];
    const float* out_w   = (const float*)d_in[10];
    const float* out_b   = (const float*)d_in[11];

    char* ws = (char*)d_ws;
    float*  lenT = (float*)(ws + OFF_LENT);
    float*  ipdT = (float*)(ws + OFF_IPDT);
    bf16_t* wfi  = (bf16_t*)(ws + OFF_WIH);
    bf16_t* wfh  = (bf16_t*)(ws + OFF_WHH);
    bf16_t* gi   = (bf16_t*)(ws + OFF_GI);

    prep_kernel<<<302, 256, 0, stream>>>(len_emb, ipd_emb, fc_w, fc_b,
                                         w_ih, w_hh, lenT, ipdT, wfi, wfh);
    fused_kernel<<<256, 512, 0, stream>>>(len_x, ipd_x, lenT, ipdT, wfi, wfh,
                                          b_ih, b_hh, gi, out_w, out_b,
                                          (float*)d_out);
}